// Round 1
// baseline (379.430 us; speedup 1.0000x reference)
//
#include <hip/hip_runtime.h>
#include <hip/hip_bf16.h>
#include <stdint.h>
#include <stddef.h>

#define NROWS 8192
#define DDIM  512              // floats per input row; ALSO bytes per fp8 row
#define TILE  128
#define BKB   128              // fp8 K-elements (=bytes) per LDS stage
#define NBLK  (NROWS / TILE)   // 64

static_assert(NBLK == 64, "bj extraction assumes 64 col-blocks");

typedef float f32x4 __attribute__((ext_vector_type(4)));
typedef int   i32x4 __attribute__((ext_vector_type(4)));
typedef int   i32x8 __attribute__((ext_vector_type(8)));

// async global->LDS, 16B per lane; LDS dest is wave-uniform base + lane*16
__device__ __forceinline__ void async_copy16(const void* g, void* l) {
    __builtin_amdgcn_global_load_lds(
        (const __attribute__((address_space(1))) uint32_t*)g,
        (__attribute__((address_space(3))) uint32_t*)l,
        16, 0, 0);
}

// -------- prep: zero accumulators + normalize both matrices to fp8 e4m3 --------
// grid = 4096: blocks [0,2048) cxr->cn8, [2048,4096) ehr->en8.
// blocks [0,64) zero rowsum/colsum (64*256 = 16384 = 2N floats); block 0 zeroes out[0].
__global__ __launch_bounds__(256) void prep_kernel(
    const float* __restrict__ CXR, const float* __restrict__ EHR,
    uint32_t* __restrict__ CN8, uint32_t* __restrict__ EN8,
    float* __restrict__ rowsum /* colsum follows contiguously */,
    float* __restrict__ out)
{
    if (blockIdx.x < 64) {
        rowsum[blockIdx.x * 256 + threadIdx.x] = 0.f;
        if (blockIdx.x == 0 && threadIdx.x == 0) out[0] = 0.f;
    }
    const int half = (blockIdx.x >= 2048);
    const float* X = half ? EHR : CXR;
    uint32_t* Y = half ? EN8 : CN8;
    const int row  = (blockIdx.x & 2047) * 4 + (threadIdx.x >> 6);
    const int lane = threadIdx.x & 63;
    const float* xr = X + (size_t)row * DDIM;
    float4 v0 = ((const float4*)xr)[lane];        // elems lane*4   .. +3
    float4 v1 = ((const float4*)xr)[lane + 64];   // elems 256+lane*4 .. +3
    float ss = v0.x*v0.x + v0.y*v0.y + v0.z*v0.z + v0.w*v0.w
             + v1.x*v1.x + v1.y*v1.y + v1.z*v1.z + v1.w*v1.w;
    #pragma unroll
    for (int d = 1; d < 64; d <<= 1) ss += __shfl_xor(ss, d);
    const float sc = 1.0f / fmaxf(sqrtf(ss), 1e-8f);
    uint32_t* yr = Y + (size_t)row * (DDIM / 4);
    int w0 = __builtin_amdgcn_cvt_pk_fp8_f32(v0.x*sc, v0.y*sc, 0, false);
    w0     = __builtin_amdgcn_cvt_pk_fp8_f32(v0.z*sc, v0.w*sc, w0, true);
    int w1 = __builtin_amdgcn_cvt_pk_fp8_f32(v1.x*sc, v1.y*sc, 0, false);
    w1     = __builtin_amdgcn_cvt_pk_fp8_f32(v1.z*sc, v1.w*sc, w1, true);
    yr[lane]      = (uint32_t)w0;   // bytes = elems lane*4..+3 in k order
    yr[lane + 64] = (uint32_t)w1;
}

// -------- fused S = cn·enT GEMM (MX-scaled fp8, 16x16x128, scale=1.0) + exp + reductions ----
// Round-8 change: non-scaled mfma_f32_16x16x32_fp8_fp8 (bf16-rate, ~2.05 PF, was the
// 42%-MfmaUtil bottleneck) -> mfma_scale_f32_16x16x128_f8f6f4 with both scales
// pinned to 0x7F (E8M0 exponent 0 = x1.0): same products, 2.27x the MFMA rate,
// 4x fewer MFMA instructions. Each lane supplies 32 contiguous K-bytes
// (k = (lane>>4)*32..+31 -> 16B-units u=2q, 2q+1); within a 16-lane phase group
// q is constant so slot = u^(lcol&7) still covers all 8 swizzle slots ->
// conflict-free, staging side unchanged. Holding 4 A-frags = 32 VGPR (was 16)
// pushes unified regs past the 128 cap, so launch_bounds (256,4)->(256,3)
// (achieved occupancy was ~11 waves/CU anyway).
// 256 threads / 4 waves, wave tile 64x64, acc 4x4 f32x4 (AGPRs).
__global__ __launch_bounds__(256, 3) void gemm_loss_kernel(
    const uint8_t* __restrict__ A,   // cn fp8 [N][512 B]
    const uint8_t* __restrict__ B,   // en fp8 [N][512 B]
    const float* __restrict__ temp_p,
    float* __restrict__ rowsum,
    float* __restrict__ colsum,
    float* __restrict__ diagv)
{
    __shared__ uint8_t As[TILE * BKB];   // 16 KB
    __shared__ uint8_t Bs[TILE * BKB];   // 16 KB

    const int tid  = threadIdx.x;
    const int lane = tid & 63;
    const int wv   = tid >> 6;          // wave 0..3
    const int wi   = (wv >> 1) * 64;    // wave row offset in tile
    const int wj   = (wv & 1) * 64;     // wave col offset in tile
    const int lcol = lane & 15;
    const int q    = lane >> 4;
    const int u0   = q << 1;            // first 16B k-unit this lane feeds to MFMA

    const int bi = blockIdx.x & (NBLK - 1);
    const int bj = blockIdx.x >> 6;
    const int row0 = bi * TILE;
    const int col0 = bj * TILE;

    // staging: wave wv loads rows [wv*32, wv*32+32) of both tiles, 4 chunks of 8 rows
    const int sr = lane >> 3;            // row within 8-row chunk
    const int su = (lane & 7) ^ sr;      // 16B-unit fetched by this lane (swizzle inverse)
    const uint8_t* Ag = A + (size_t)(row0 + wv * 32 + sr) * DDIM + su * 16;
    const uint8_t* Bg = B + (size_t)(col0 + wv * 32 + sr) * DDIM + su * 16;

    f32x4 acc[4][4] = {};
    const int SC1 = 0x7F7F7F7F;          // E8M0 scale 1.0 in every byte

    for (int k0 = 0; k0 < DDIM; k0 += BKB) {   // 4 stages
        __syncthreads();   // previous stage's LDS reads done before overwrite
        #pragma unroll
        for (int c = 0; c < 4; ++c) {
            async_copy16(Ag + (size_t)(c * 8) * DDIM + k0, &As[(wv * 32 + c * 8) * BKB]);
            async_copy16(Bg + (size_t)(c * 8) * DDIM + k0, &Bs[(wv * 32 + c * 8) * BKB]);
        }
        __syncthreads();   // drains vmcnt before s_barrier

        // A fragments: 32 B per lane = k (q*32 .. q*32+31), units u0, u0+1
        i32x8 af[4];
        #pragma unroll
        for (int mt = 0; mt < 4; ++mt) {
            const int r = wi + mt * 16 + lcol;
            const uint8_t* base = &As[r * BKB];
            i32x4 lo = *(const i32x4*)&base[((u0    ) ^ (r & 7)) * 16];
            i32x4 hi = *(const i32x4*)&base[((u0 + 1) ^ (r & 7)) * 16];
            af[mt] = __builtin_shufflevector(lo, hi, 0, 1, 2, 3, 4, 5, 6, 7);
        }
        // B fragments streamed: one frag feeds 4 MFMAs
        #pragma unroll
        for (int nt = 0; nt < 4; ++nt) {
            const int r = wj + nt * 16 + lcol;
            const uint8_t* base = &Bs[r * BKB];
            i32x4 lo = *(const i32x4*)&base[((u0    ) ^ (r & 7)) * 16];
            i32x4 hi = *(const i32x4*)&base[((u0 + 1) ^ (r & 7)) * 16];
            i32x8 bf = __builtin_shufflevector(lo, hi, 0, 1, 2, 3, 4, 5, 6, 7);
            #pragma unroll
            for (int mt = 0; mt < 4; ++mt)
                acc[mt][nt] = __builtin_amdgcn_mfma_scale_f32_16x16x128_f8f6f4(
                    af[mt], bf, acc[mt][nt],
                    0 /*cbsz: A=fp8 e4m3*/, 0 /*blgp: B=fp8 e4m3*/,
                    0, SC1, 0, SC1);
        }
    }

    // ---- epilogue: e = exp(s - M) = 2^(c2*acc - c2), M = 1/T (max possible) ----
    const float invT = 1.0f / temp_p[0];
    const float c2   = invT * 1.442695040888963f;   // log2(e)/T

    float rs[4][4];   // per-lane row partials [mt][reg]
    float cs[4];      // per-lane col partials [nt]
    #pragma unroll
    for (int mt = 0; mt < 4; ++mt)
        #pragma unroll
        for (int r = 0; r < 4; ++r) rs[mt][r] = 0.f;
    #pragma unroll
    for (int nt = 0; nt < 4; ++nt) cs[nt] = 0.f;

    #pragma unroll
    for (int mt = 0; mt < 4; ++mt) {
        #pragma unroll
        for (int nt = 0; nt < 4; ++nt) {
            #pragma unroll
            for (int r = 0; r < 4; ++r) {
                // C/D layout: col = lane&15, row = quad*4 + reg  [m89/m91]
                const int gi = row0 + wi + mt * 16 + q * 4 + r;
                const int gj = col0 + wj + nt * 16 + lcol;
                const float a = acc[mt][nt][r];
                float e;
                if (gi == gj) { diagv[gi] = a * invT; e = 0.f; }
                else          { e = __builtin_amdgcn_exp2f(fmaf(a, c2, -c2)); }
                rs[mt][r] += e;
                cs[nt]    += e;
            }
        }
    }

    // row sums: reduce across the 16 columns (lane bits 0..3)
    #pragma unroll
    for (int d = 1; d < 16; d <<= 1)
        #pragma unroll
        for (int mt = 0; mt < 4; ++mt)
            #pragma unroll
            for (int r = 0; r < 4; ++r)
                rs[mt][r] += __shfl_xor(rs[mt][r], d);

    // col sums: reduce across the 4 quads (lane bits 4..5)
    #pragma unroll
    for (int d = 16; d < 64; d <<= 1)
        #pragma unroll
        for (int nt = 0; nt < 4; ++nt)
            cs[nt] += __shfl_xor(cs[nt], d);

    if (lcol == 0) {
        #pragma unroll
        for (int mt = 0; mt < 4; ++mt)
            #pragma unroll
            for (int r = 0; r < 4; ++r)
                atomicAdd(&rowsum[row0 + wi + mt * 16 + q * 4 + r], rs[mt][r]);
    }
    if (q == 0) {
        #pragma unroll
        for (int nt = 0; nt < 4; ++nt)
            atomicAdd(&colsum[col0 + wj + nt * 16 + lcol], cs[nt]);
    }
}

// -------- final scalar: loss = mean_i( 2M + log(rowsum_i) + log(colsum_i) - 2*diag_i ) ----
__global__ __launch_bounds__(256) void finalize_kernel(
    const float* __restrict__ rowsum, const float* __restrict__ colsum,
    const float* __restrict__ diagv,  const float* __restrict__ temp_p,
    float* __restrict__ out)
{
    __shared__ float red[4];
    const float M = 1.0f / temp_p[0];
    const int i = blockIdx.x * 256 + threadIdx.x;
    float s = 2.f * M + logf(rowsum[i]) + logf(colsum[i]) - 2.f * diagv[i];
    #pragma unroll
    for (int d = 1; d < 64; d <<= 1) s += __shfl_xor(s, d);
    if ((threadIdx.x & 63) == 0) red[threadIdx.x >> 6] = s;
    __syncthreads();
    if (threadIdx.x == 0)
        atomicAdd(out, (red[0] + red[1] + red[2] + red[3]) / (float)NROWS);
}

extern "C" void kernel_launch(void* const* d_in, const int* in_sizes, int n_in,
                              void* d_out, int out_size, void* d_ws, size_t ws_size,
                              hipStream_t stream) {
    (void)in_sizes; (void)n_in; (void)out_size; (void)ws_size;
    const float* cxr    = (const float*)d_in[0];
    const float* ehr    = (const float*)d_in[1];
    const float* temp_p = (const float*)d_in[2];
    float* out = (float*)d_out;

    // workspace: rowsum[N] | colsum[N] | diag[N] | cn fp8 [N*512B] | en fp8 (~8.1 MB)
    float* rowsum = (float*)d_ws;
    float* colsum = rowsum + NROWS;
    float* diagv  = colsum + NROWS;
    uint32_t* cn8 = (uint32_t*)(diagv + NROWS);            // 16B-aligned (96 KB offset)
    uint32_t* en8 = cn8 + (size_t)NROWS * (DDIM / 4);
    const uint8_t* cnb = (const uint8_t*)cn8;
    const uint8_t* enb = (const uint8_t*)en8;

    prep_kernel<<<4096, 256, 0, stream>>>(cxr, ehr, cn8, en8, rowsum, out);
    gemm_loss_kernel<<<NBLK * NBLK, 256, 0, stream>>>(cnb, enb, temp_p, rowsum, colsum, diagv);
    finalize_kernel<<<NROWS / 256, 256, 0, stream>>>(rowsum, colsum, diagv, temp_p, out);
}

// Round 2
// 234.085 us; speedup vs baseline: 1.6209x; 1.6209x over previous
//
#include <hip/hip_runtime.h>
#include <hip/hip_bf16.h>
#include <stdint.h>
#include <stddef.h>

#define NROWS 8192
#define DDIM  512              // floats per input row; ALSO bytes per fp8 row
#define TILE  128
#define BKB   128              // fp8 K-elements (=bytes) per LDS stage
#define NBLK  (NROWS / TILE)   // 64

static_assert(NBLK == 64, "bj extraction assumes 64 col-blocks");

typedef float f32x4 __attribute__((ext_vector_type(4)));
typedef int   i32x4 __attribute__((ext_vector_type(4)));
typedef int   i32x8 __attribute__((ext_vector_type(8)));

// async global->LDS, 16B per lane; LDS dest is wave-uniform base + lane*16
__device__ __forceinline__ void async_copy16(const void* g, void* l) {
    __builtin_amdgcn_global_load_lds(
        (const __attribute__((address_space(1))) uint32_t*)g,
        (__attribute__((address_space(3))) uint32_t*)l,
        16, 0, 0);
}

// -------- prep: zero accumulators + normalize both matrices to fp8 e4m3 --------
// grid = 4096: blocks [0,2048) cxr->cn8, [2048,4096) ehr->en8.
// blocks [0,64) zero rowsum/colsum (64*256 = 16384 = 2N floats); block 0 zeroes out[0].
__global__ __launch_bounds__(256) void prep_kernel(
    const float* __restrict__ CXR, const float* __restrict__ EHR,
    uint32_t* __restrict__ CN8, uint32_t* __restrict__ EN8,
    float* __restrict__ rowsum /* colsum follows contiguously */,
    float* __restrict__ out)
{
    if (blockIdx.x < 64) {
        rowsum[blockIdx.x * 256 + threadIdx.x] = 0.f;
        if (blockIdx.x == 0 && threadIdx.x == 0) out[0] = 0.f;
    }
    const int half = (blockIdx.x >= 2048);
    const float* X = half ? EHR : CXR;
    uint32_t* Y = half ? EN8 : CN8;
    const int row  = (blockIdx.x & 2047) * 4 + (threadIdx.x >> 6);
    const int lane = threadIdx.x & 63;
    const float* xr = X + (size_t)row * DDIM;
    float4 v0 = ((const float4*)xr)[lane];        // elems lane*4   .. +3
    float4 v1 = ((const float4*)xr)[lane + 64];   // elems 256+lane*4 .. +3
    float ss = v0.x*v0.x + v0.y*v0.y + v0.z*v0.z + v0.w*v0.w
             + v1.x*v1.x + v1.y*v1.y + v1.z*v1.z + v1.w*v1.w;
    #pragma unroll
    for (int d = 1; d < 64; d <<= 1) ss += __shfl_xor(ss, d);
    const float sc = 1.0f / fmaxf(sqrtf(ss), 1e-8f);
    uint32_t* yr = Y + (size_t)row * (DDIM / 4);
    int w0 = __builtin_amdgcn_cvt_pk_fp8_f32(v0.x*sc, v0.y*sc, 0, false);
    w0     = __builtin_amdgcn_cvt_pk_fp8_f32(v0.z*sc, v0.w*sc, w0, true);
    int w1 = __builtin_amdgcn_cvt_pk_fp8_f32(v1.x*sc, v1.y*sc, 0, false);
    w1     = __builtin_amdgcn_cvt_pk_fp8_f32(v1.z*sc, v1.w*sc, w1, true);
    yr[lane]      = (uint32_t)w0;   // bytes = elems lane*4..+3 in k order
    yr[lane + 64] = (uint32_t)w1;
}

// -------- fused S = cn·enT GEMM (MX-scaled fp8, 16x16x128, scale=1.0) + exp + reductions ----
// Round-9 change: round-8's MX port was numerically correct (absmax 0) but spilled
// catastrophically: WRITE_SIZE 729 MB / FETCH 630 MB of scratch traffic (launch_bounds
// (256,3) = ~168-reg cap vs ~140 live regs incl. five 8-aligned i32x8 tuples ->
// allocator fragmentation -> spill -> 324 us). Fix: (256,2) -> 256 unified regs/wave,
// ~110 regs headroom, zero spill. Occupancy cap 8 waves/CU (2 blocks/CU), LDS allows it.
// MX math unchanged: mfma_scale_f32_16x16x128_f8f6f4, scales pinned 0x7F (x1.0),
// 2.27x the non-scaled fp8 rate, 4x fewer MFMA instructions.
// Each lane supplies 32 contiguous K-bytes (k=(lane>>4)*32..+31 -> units u=2q,2q+1);
// slot = u^(lcol&7) keeps the 8-slot coverage -> conflict-free, staging unchanged.
// 256 threads / 4 waves, wave tile 64x64, acc 4x4 f32x4.
__global__ __launch_bounds__(256, 2) void gemm_loss_kernel(
    const uint8_t* __restrict__ A,   // cn fp8 [N][512 B]
    const uint8_t* __restrict__ B,   // en fp8 [N][512 B]
    const float* __restrict__ temp_p,
    float* __restrict__ rowsum,
    float* __restrict__ colsum,
    float* __restrict__ diagv)
{
    __shared__ uint8_t As[TILE * BKB];   // 16 KB
    __shared__ uint8_t Bs[TILE * BKB];   // 16 KB

    const int tid  = threadIdx.x;
    const int lane = tid & 63;
    const int wv   = tid >> 6;          // wave 0..3
    const int wi   = (wv >> 1) * 64;    // wave row offset in tile
    const int wj   = (wv & 1) * 64;     // wave col offset in tile
    const int lcol = lane & 15;
    const int q    = lane >> 4;
    const int u0   = q << 1;            // first 16B k-unit this lane feeds to MFMA

    const int bi = blockIdx.x & (NBLK - 1);
    const int bj = blockIdx.x >> 6;
    const int row0 = bi * TILE;
    const int col0 = bj * TILE;

    // staging: wave wv loads rows [wv*32, wv*32+32) of both tiles, 4 chunks of 8 rows
    const int sr = lane >> 3;            // row within 8-row chunk
    const int su = (lane & 7) ^ sr;      // 16B-unit fetched by this lane (swizzle inverse)
    const uint8_t* Ag = A + (size_t)(row0 + wv * 32 + sr) * DDIM + su * 16;
    const uint8_t* Bg = B + (size_t)(col0 + wv * 32 + sr) * DDIM + su * 16;

    f32x4 acc[4][4] = {};
    const int SC1 = 0x7F7F7F7F;          // E8M0 scale 1.0 in every byte

    for (int k0 = 0; k0 < DDIM; k0 += BKB) {   // 4 stages
        __syncthreads();   // previous stage's LDS reads done before overwrite
        #pragma unroll
        for (int c = 0; c < 4; ++c) {
            async_copy16(Ag + (size_t)(c * 8) * DDIM + k0, &As[(wv * 32 + c * 8) * BKB]);
            async_copy16(Bg + (size_t)(c * 8) * DDIM + k0, &Bs[(wv * 32 + c * 8) * BKB]);
        }
        __syncthreads();   // drains vmcnt before s_barrier

        // A fragments: 32 B per lane = k (q*32 .. q*32+31), units u0, u0+1
        i32x8 af[4];
        #pragma unroll
        for (int mt = 0; mt < 4; ++mt) {
            const int r = wi + mt * 16 + lcol;
            const uint8_t* base = &As[r * BKB];
            i32x4 lo = *(const i32x4*)&base[((u0    ) ^ (r & 7)) * 16];
            i32x4 hi = *(const i32x4*)&base[((u0 + 1) ^ (r & 7)) * 16];
            af[mt] = __builtin_shufflevector(lo, hi, 0, 1, 2, 3, 4, 5, 6, 7);
        }
        // B fragments streamed: one frag feeds 4 MFMAs
        #pragma unroll
        for (int nt = 0; nt < 4; ++nt) {
            const int r = wj + nt * 16 + lcol;
            const uint8_t* base = &Bs[r * BKB];
            i32x4 lo = *(const i32x4*)&base[((u0    ) ^ (r & 7)) * 16];
            i32x4 hi = *(const i32x4*)&base[((u0 + 1) ^ (r & 7)) * 16];
            i32x8 bf = __builtin_shufflevector(lo, hi, 0, 1, 2, 3, 4, 5, 6, 7);
            #pragma unroll
            for (int mt = 0; mt < 4; ++mt)
                acc[mt][nt] = __builtin_amdgcn_mfma_scale_f32_16x16x128_f8f6f4(
                    af[mt], bf, acc[mt][nt],
                    0 /*cbsz: A=fp8 e4m3*/, 0 /*blgp: B=fp8 e4m3*/,
                    0, SC1, 0, SC1);
        }
    }

    // ---- epilogue: e = exp(s - M) = 2^(c2*acc - c2), M = 1/T (max possible) ----
    const float invT = 1.0f / temp_p[0];
    const float c2   = invT * 1.442695040888963f;   // log2(e)/T

    float rs[4][4];   // per-lane row partials [mt][reg]
    float cs[4];      // per-lane col partials [nt]
    #pragma unroll
    for (int mt = 0; mt < 4; ++mt)
        #pragma unroll
        for (int r = 0; r < 4; ++r) rs[mt][r] = 0.f;
    #pragma unroll
    for (int nt = 0; nt < 4; ++nt) cs[nt] = 0.f;

    #pragma unroll
    for (int mt = 0; mt < 4; ++mt) {
        #pragma unroll
        for (int nt = 0; nt < 4; ++nt) {
            #pragma unroll
            for (int r = 0; r < 4; ++r) {
                // C/D layout: col = lane&15, row = quad*4 + reg  [m89/m91]
                const int gi = row0 + wi + mt * 16 + q * 4 + r;
                const int gj = col0 + wj + nt * 16 + lcol;
                const float a = acc[mt][nt][r];
                float e;
                if (gi == gj) { diagv[gi] = a * invT; e = 0.f; }
                else          { e = __builtin_amdgcn_exp2f(fmaf(a, c2, -c2)); }
                rs[mt][r] += e;
                cs[nt]    += e;
            }
        }
    }

    // row sums: reduce across the 16 columns (lane bits 0..3)
    #pragma unroll
    for (int d = 1; d < 16; d <<= 1)
        #pragma unroll
        for (int mt = 0; mt < 4; ++mt)
            #pragma unroll
            for (int r = 0; r < 4; ++r)
                rs[mt][r] += __shfl_xor(rs[mt][r], d);

    // col sums: reduce across the 4 quads (lane bits 4..5)
    #pragma unroll
    for (int d = 16; d < 64; d <<= 1)
        #pragma unroll
        for (int nt = 0; nt < 4; ++nt)
            cs[nt] += __shfl_xor(cs[nt], d);

    if (lcol == 0) {
        #pragma unroll
        for (int mt = 0; mt < 4; ++mt)
            #pragma unroll
            for (int r = 0; r < 4; ++r)
                atomicAdd(&rowsum[row0 + wi + mt * 16 + q * 4 + r], rs[mt][r]);
    }
    if (q == 0) {
        #pragma unroll
        for (int nt = 0; nt < 4; ++nt)
            atomicAdd(&colsum[col0 + wj + nt * 16 + lcol], cs[nt]);
    }
}

// -------- final scalar: loss = mean_i( 2M + log(rowsum_i) + log(colsum_i) - 2*diag_i ) ----
__global__ __launch_bounds__(256) void finalize_kernel(
    const float* __restrict__ rowsum, const float* __restrict__ colsum,
    const float* __restrict__ diagv,  const float* __restrict__ temp_p,
    float* __restrict__ out)
{
    __shared__ float red[4];
    const float M = 1.0f / temp_p[0];
    const int i = blockIdx.x * 256 + threadIdx.x;
    float s = 2.f * M + logf(rowsum[i]) + logf(colsum[i]) - 2.f * diagv[i];
    #pragma unroll
    for (int d = 1; d < 64; d <<= 1) s += __shfl_xor(s, d);
    if ((threadIdx.x & 63) == 0) red[threadIdx.x >> 6] = s;
    __syncthreads();
    if (threadIdx.x == 0)
        atomicAdd(out, (red[0] + red[1] + red[2] + red[3]) / (float)NROWS);
}

extern "C" void kernel_launch(void* const* d_in, const int* in_sizes, int n_in,
                              void* d_out, int out_size, void* d_ws, size_t ws_size,
                              hipStream_t stream) {
    (void)in_sizes; (void)n_in; (void)out_size; (void)ws_size;
    const float* cxr    = (const float*)d_in[0];
    const float* ehr    = (const float*)d_in[1];
    const float* temp_p = (const float*)d_in[2];
    float* out = (float*)d_out;

    // workspace: rowsum[N] | colsum[N] | diag[N] | cn fp8 [N*512B] | en fp8 (~8.1 MB)
    float* rowsum = (float*)d_ws;
    float* colsum = rowsum + NROWS;
    float* diagv  = colsum + NROWS;
    uint32_t* cn8 = (uint32_t*)(diagv + NROWS);            // 16B-aligned (96 KB offset)
    uint32_t* en8 = cn8 + (size_t)NROWS * (DDIM / 4);
    const uint8_t* cnb = (const uint8_t*)cn8;
    const uint8_t* enb = (const uint8_t*)en8;

    prep_kernel<<<4096, 256, 0, stream>>>(cxr, ehr, cn8, en8, rowsum, out);
    gemm_loss_kernel<<<NBLK * NBLK, 256, 0, stream>>>(cnb, enb, temp_p, rowsum, colsum, diagv);
    finalize_kernel<<<NROWS / 256, 256, 0, stream>>>(rowsum, colsum, diagv, temp_p, out);
}

// Round 4
// 202.204 us; speedup vs baseline: 1.8765x; 1.1577x over previous
//
#include <hip/hip_runtime.h>
#include <hip/hip_bf16.h>
#include <stdint.h>
#include <stddef.h>

#define NROWS 8192
#define DDIM  512              // floats per input row; ALSO bytes per fp8 row
#define TILE  128
#define BKB   128              // fp8 K-elements (=bytes) per LDS stage
#define NBLK  (NROWS / TILE)   // 64

static_assert(NBLK == 64, "bj extraction assumes 64 col-blocks");

typedef float f32x4 __attribute__((ext_vector_type(4)));
typedef int   i32x4 __attribute__((ext_vector_type(4)));
typedef int   i32x8 __attribute__((ext_vector_type(8)));

// async global->LDS, 16B per lane; LDS dest is wave-uniform base + lane*16
__device__ __forceinline__ void async_copy16(const void* g, void* l) {
    __builtin_amdgcn_global_load_lds(
        (const __attribute__((address_space(1))) uint32_t*)g,
        (__attribute__((address_space(3))) uint32_t*)l,
        16, 0, 0);
}

// -------- prep: zero accumulators + normalize both matrices to fp8 e4m3 --------
// grid = 4096: blocks [0,2048) cxr->cn8, [2048,4096) ehr->en8.
// blocks [0,64) zero rowsum/colsum (64*256 = 16384 = 2N floats); block 0 zeroes out[0].
__global__ __launch_bounds__(256) void prep_kernel(
    const float* __restrict__ CXR, const float* __restrict__ EHR,
    uint32_t* __restrict__ CN8, uint32_t* __restrict__ EN8,
    float* __restrict__ rowsum /* colsum follows contiguously */,
    float* __restrict__ out)
{
    if (blockIdx.x < 64) {
        rowsum[blockIdx.x * 256 + threadIdx.x] = 0.f;
        if (blockIdx.x == 0 && threadIdx.x == 0) out[0] = 0.f;
    }
    const int half = (blockIdx.x >= 2048);
    const float* X = half ? EHR : CXR;
    uint32_t* Y = half ? EN8 : CN8;
    const int row  = (blockIdx.x & 2047) * 4 + (threadIdx.x >> 6);
    const int lane = threadIdx.x & 63;
    const float* xr = X + (size_t)row * DDIM;
    float4 v0 = ((const float4*)xr)[lane];        // elems lane*4   .. +3
    float4 v1 = ((const float4*)xr)[lane + 64];   // elems 256+lane*4 .. +3
    float ss = v0.x*v0.x + v0.y*v0.y + v0.z*v0.z + v0.w*v0.w
             + v1.x*v1.x + v1.y*v1.y + v1.z*v1.z + v1.w*v1.w;
    #pragma unroll
    for (int d = 1; d < 64; d <<= 1) ss += __shfl_xor(ss, d);
    const float sc = 1.0f / fmaxf(sqrtf(ss), 1e-8f);
    uint32_t* yr = Y + (size_t)row * (DDIM / 4);
    int w0 = __builtin_amdgcn_cvt_pk_fp8_f32(v0.x*sc, v0.y*sc, 0, false);
    w0     = __builtin_amdgcn_cvt_pk_fp8_f32(v0.z*sc, v0.w*sc, w0, true);
    int w1 = __builtin_amdgcn_cvt_pk_fp8_f32(v1.x*sc, v1.y*sc, 0, false);
    w1     = __builtin_amdgcn_cvt_pk_fp8_f32(v1.z*sc, v1.w*sc, w1, true);
    yr[lane]      = (uint32_t)w0;   // bytes = elems lane*4..+3 in k order
    yr[lane + 64] = (uint32_t)w1;
}

// -------- fused S = cn·enT GEMM (MX-scaled fp8, 16x16x128, scale=1.0) + exp + reductions ----
// Round-10 (re-run; round-3 bench was a GPU-acquisition timeout, no data):
// rounds 8/9 proved the MX math correct (absmax 0) but spilled at both
// (256,3) [729 MB scratch writes] and (256,2) [360 MB]: the allocator used the full
// budget (arch VGPR 84 -> 128) and still ran out -- peak pressure with FIVE live
// 8-aligned i32x8 tuples + 64 acc regs exceeds 256 under alignment fragmentation.
// Two-sided fix, MX math unchanged:
//   (a) __launch_bounds__(256,1): allow up to 512 regs; runtime occupancy floats.
//   (b) fragment streaming restructured so at most THREE 8-tuples are live:
//       outer nt2 holds bf2[2] (16 regs); af is built per-mt right before its two
//       MFMAs and dies. Peak fragment regs 40 -> 24. Cost: A-frags read twice per
//       stage (24 vs 16 ds_read_b128/wave/stage) -- LDS stays far off critical path
//       (~1.5k cyc/stage/CU vs ~4.4k cyc MFMA).
// mfma_scale_f32_16x16x128_f8f6f4, scales pinned 0x7F (x1.0) = exact same products
// as non-scaled fp8 at 2.27x the rate, 4x fewer MFMA instructions.
// Lane k-slice: k=(lane>>4)*32..+31 -> 16B-units u=2q,2q+1; slot u^(r&7) keeps the
// 8-lane phase groups covering 8 distinct 16B slots -> conflict-free; staging unchanged.
// 256 threads / 4 waves, wave tile 64x64, acc 4x4 f32x4.
__global__ __launch_bounds__(256, 1) void gemm_loss_kernel(
    const uint8_t* __restrict__ A,   // cn fp8 [N][512 B]
    const uint8_t* __restrict__ B,   // en fp8 [N][512 B]
    const float* __restrict__ temp_p,
    float* __restrict__ rowsum,
    float* __restrict__ colsum,
    float* __restrict__ diagv)
{
    __shared__ uint8_t As[TILE * BKB];   // 16 KB
    __shared__ uint8_t Bs[TILE * BKB];   // 16 KB

    const int tid  = threadIdx.x;
    const int lane = tid & 63;
    const int wv   = tid >> 6;          // wave 0..3
    const int wi   = (wv >> 1) * 64;    // wave row offset in tile
    const int wj   = (wv & 1) * 64;     // wave col offset in tile
    const int lcol = lane & 15;
    const int q    = lane >> 4;
    const int u0   = q << 1;            // first 16B k-unit this lane feeds to MFMA

    const int bi = blockIdx.x & (NBLK - 1);
    const int bj = blockIdx.x >> 6;
    const int row0 = bi * TILE;
    const int col0 = bj * TILE;

    // staging: wave wv loads rows [wv*32, wv*32+32) of both tiles, 4 chunks of 8 rows
    const int sr = lane >> 3;            // row within 8-row chunk
    const int su = (lane & 7) ^ sr;      // 16B-unit fetched by this lane (swizzle inverse)
    const uint8_t* Ag = A + (size_t)(row0 + wv * 32 + sr) * DDIM + su * 16;
    const uint8_t* Bg = B + (size_t)(col0 + wv * 32 + sr) * DDIM + su * 16;

    f32x4 acc[4][4] = {};
    const int SC1 = 0x7F7F7F7F;          // E8M0 scale 1.0 in every byte

    for (int k0 = 0; k0 < DDIM; k0 += BKB) {   // 4 stages
        __syncthreads();   // previous stage's LDS reads done before overwrite
        #pragma unroll
        for (int c = 0; c < 4; ++c) {
            async_copy16(Ag + (size_t)(c * 8) * DDIM + k0, &As[(wv * 32 + c * 8) * BKB]);
            async_copy16(Bg + (size_t)(c * 8) * DDIM + k0, &Bs[(wv * 32 + c * 8) * BKB]);
        }
        __syncthreads();   // drains vmcnt before s_barrier

        #pragma unroll
        for (int nt2 = 0; nt2 < 2; ++nt2) {
            // hold 2 B fragments (16 regs)
            i32x8 bf2[2];
            #pragma unroll
            for (int j = 0; j < 2; ++j) {
                const int r = wj + (nt2 * 2 + j) * 16 + lcol;
                const uint8_t* base = &Bs[r * BKB];
                i32x4 lo = *(const i32x4*)&base[((u0    ) ^ (r & 7)) * 16];
                i32x4 hi = *(const i32x4*)&base[((u0 + 1) ^ (r & 7)) * 16];
                bf2[j] = __builtin_shufflevector(lo, hi, 0, 1, 2, 3, 4, 5, 6, 7);
            }
            // stream A fragments: each built just before its 2 MFMAs, then dead
            #pragma unroll
            for (int mt = 0; mt < 4; ++mt) {
                const int r = wi + mt * 16 + lcol;
                const uint8_t* base = &As[r * BKB];
                i32x4 lo = *(const i32x4*)&base[((u0    ) ^ (r & 7)) * 16];
                i32x4 hi = *(const i32x4*)&base[((u0 + 1) ^ (r & 7)) * 16];
                i32x8 af = __builtin_shufflevector(lo, hi, 0, 1, 2, 3, 4, 5, 6, 7);
                acc[mt][nt2 * 2]     = __builtin_amdgcn_mfma_scale_f32_16x16x128_f8f6f4(
                    af, bf2[0], acc[mt][nt2 * 2],
                    0 /*cbsz: A=fp8 e4m3*/, 0 /*blgp: B=fp8 e4m3*/,
                    0, SC1, 0, SC1);
                acc[mt][nt2 * 2 + 1] = __builtin_amdgcn_mfma_scale_f32_16x16x128_f8f6f4(
                    af, bf2[1], acc[mt][nt2 * 2 + 1],
                    0, 0, 0, SC1, 0, SC1);
            }
        }
    }

    // ---- epilogue: e = exp(s - M) = 2^(c2*acc - c2), M = 1/T (max possible) ----
    const float invT = 1.0f / temp_p[0];
    const float c2   = invT * 1.442695040888963f;   // log2(e)/T

    float rs[4][4];   // per-lane row partials [mt][reg]
    float cs[4];      // per-lane col partials [nt]
    #pragma unroll
    for (int mt = 0; mt < 4; ++mt)
        #pragma unroll
        for (int r = 0; r < 4; ++r) rs[mt][r] = 0.f;
    #pragma unroll
    for (int nt = 0; nt < 4; ++nt) cs[nt] = 0.f;

    #pragma unroll
    for (int mt = 0; mt < 4; ++mt) {
        #pragma unroll
        for (int nt = 0; nt < 4; ++nt) {
            #pragma unroll
            for (int r = 0; r < 4; ++r) {
                // C/D layout: col = lane&15, row = quad*4 + reg  [m89/m91]
                const int gi = row0 + wi + mt * 16 + q * 4 + r;
                const int gj = col0 + wj + nt * 16 + lcol;
                const float a = acc[mt][nt][r];
                float e;
                if (gi == gj) { diagv[gi] = a * invT; e = 0.f; }
                else          { e = __builtin_amdgcn_exp2f(fmaf(a, c2, -c2)); }
                rs[mt][r] += e;
                cs[nt]    += e;
            }
        }
    }

    // row sums: reduce across the 16 columns (lane bits 0..3)
    #pragma unroll
    for (int d = 1; d < 16; d <<= 1)
        #pragma unroll
        for (int mt = 0; mt < 4; ++mt)
            #pragma unroll
            for (int r = 0; r < 4; ++r)
                rs[mt][r] += __shfl_xor(rs[mt][r], d);

    // col sums: reduce across the 4 quads (lane bits 4..5)
    #pragma unroll
    for (int d = 16; d < 64; d <<= 1)
        #pragma unroll
        for (int nt = 0; nt < 4; ++nt)
            cs[nt] += __shfl_xor(cs[nt], d);

    if (lcol == 0) {
        #pragma unroll
        for (int mt = 0; mt < 4; ++mt)
            #pragma unroll
            for (int r = 0; r < 4; ++r)
                atomicAdd(&rowsum[row0 + wi + mt * 16 + q * 4 + r], rs[mt][r]);
    }
    if (q == 0) {
        #pragma unroll
        for (int nt = 0; nt < 4; ++nt)
            atomicAdd(&colsum[col0 + wj + nt * 16 + lcol], cs[nt]);
    }
}

// -------- final scalar: loss = mean_i( 2M + log(rowsum_i) + log(colsum_i) - 2*diag_i ) ----
__global__ __launch_bounds__(256) void finalize_kernel(
    const float* __restrict__ rowsum, const float* __restrict__ colsum,
    const float* __restrict__ diagv,  const float* __restrict__ temp_p,
    float* __restrict__ out)
{
    __shared__ float red[4];
    const float M = 1.0f / temp_p[0];
    const int i = blockIdx.x * 256 + threadIdx.x;
    float s = 2.f * M + logf(rowsum[i]) + logf(colsum[i]) - 2.f * diagv[i];
    #pragma unroll
    for (int d = 1; d < 64; d <<= 1) s += __shfl_xor(s, d);
    if ((threadIdx.x & 63) == 0) red[threadIdx.x >> 6] = s;
    __syncthreads();
    if (threadIdx.x == 0)
        atomicAdd(out, (red[0] + red[1] + red[2] + red[3]) / (float)NROWS);
}

extern "C" void kernel_launch(void* const* d_in, const int* in_sizes, int n_in,
                              void* d_out, int out_size, void* d_ws, size_t ws_size,
                              hipStream_t stream) {
    (void)in_sizes; (void)n_in; (void)out_size; (void)ws_size;
    const float* cxr    = (const float*)d_in[0];
    const float* ehr    = (const float*)d_in[1];
    const float* temp_p = (const float*)d_in[2];
    float* out = (float*)d_out;

    // workspace: rowsum[N] | colsum[N] | diag[N] | cn fp8 [N*512B] | en fp8 (~8.1 MB)
    float* rowsum = (float*)d_ws;
    float* colsum = rowsum + NROWS;
    float* diagv  = colsum + NROWS;
    uint32_t* cn8 = (uint32_t*)(diagv + NROWS);            // 16B-aligned (96 KB offset)
    uint32_t* en8 = cn8 + (size_t)NROWS * (DDIM / 4);
    const uint8_t* cnb = (const uint8_t*)cn8;
    const uint8_t* enb = (const uint8_t*)en8;

    prep_kernel<<<4096, 256, 0, stream>>>(cxr, ehr, cn8, en8, rowsum, out);
    gemm_loss_kernel<<<NBLK * NBLK, 256, 0, stream>>>(cnb, enb, temp_p, rowsum, colsum, diagv);
    finalize_kernel<<<NROWS / 256, 256, 0, stream>>>(rowsum, colsum, diagv, temp_p, out);
}

// Round 8
// 197.324 us; speedup vs baseline: 1.9229x; 1.0247x over previous
//
#include <hip/hip_runtime.h>
#include <hip/hip_bf16.h>
#include <stdint.h>
#include <stddef.h>

#define NROWS 8192
#define DDIM  512              // floats per input row; ALSO bytes per fp8 row
#define TILE  128
#define BKB   128              // fp8 K-elements (=bytes) per LDS stage
#define NBLK  (NROWS / TILE)   // 64

static_assert(NBLK == 64, "bj extraction assumes 64 col-blocks");

typedef float f32x4 __attribute__((ext_vector_type(4)));
typedef int   i32x4 __attribute__((ext_vector_type(4)));
typedef int   i32x8 __attribute__((ext_vector_type(8)));

// async global->LDS, 16B per lane; LDS dest is wave-uniform base + lane*16
__device__ __forceinline__ void async_copy16(const void* g, void* l) {
    __builtin_amdgcn_global_load_lds(
        (const __attribute__((address_space(1))) uint32_t*)g,
        (__attribute__((address_space(3))) uint32_t*)l,
        16, 0, 0);
}

// -------- prep: zero accumulators + normalize both matrices to fp8 e4m3 --------
// grid = 4096: blocks [0,2048) cxr->cn8, [2048,4096) ehr->en8.
// blocks [0,64) zero rowsum/colsum (64*256 = 16384 = 2N floats); block 0 zeroes out[0].
__global__ __launch_bounds__(256) void prep_kernel(
    const float* __restrict__ CXR, const float* __restrict__ EHR,
    uint32_t* __restrict__ CN8, uint32_t* __restrict__ EN8,
    float* __restrict__ rowsum /* colsum follows contiguously */,
    float* __restrict__ out)
{
    if (blockIdx.x < 64) {
        rowsum[blockIdx.x * 256 + threadIdx.x] = 0.f;
        if (blockIdx.x == 0 && threadIdx.x == 0) out[0] = 0.f;
    }
    const int half = (blockIdx.x >= 2048);
    const float* X = half ? EHR : CXR;
    uint32_t* Y = half ? EN8 : CN8;
    const int row  = (blockIdx.x & 2047) * 4 + (threadIdx.x >> 6);
    const int lane = threadIdx.x & 63;
    const float* xr = X + (size_t)row * DDIM;
    float4 v0 = ((const float4*)xr)[lane];        // elems lane*4   .. +3
    float4 v1 = ((const float4*)xr)[lane + 64];   // elems 256+lane*4 .. +3
    float ss = v0.x*v0.x + v0.y*v0.y + v0.z*v0.z + v0.w*v0.w
             + v1.x*v1.x + v1.y*v1.y + v1.z*v1.z + v1.w*v1.w;
    #pragma unroll
    for (int d = 1; d < 64; d <<= 1) ss += __shfl_xor(ss, d);
    const float sc = 1.0f / fmaxf(sqrtf(ss), 1e-8f);
    uint32_t* yr = Y + (size_t)row * (DDIM / 4);
    int w0 = __builtin_amdgcn_cvt_pk_fp8_f32(v0.x*sc, v0.y*sc, 0, false);
    w0     = __builtin_amdgcn_cvt_pk_fp8_f32(v0.z*sc, v0.w*sc, w0, true);
    int w1 = __builtin_amdgcn_cvt_pk_fp8_f32(v1.x*sc, v1.y*sc, 0, false);
    w1     = __builtin_amdgcn_cvt_pk_fp8_f32(v1.z*sc, v1.w*sc, w1, true);
    yr[lane]      = (uint32_t)w0;   // bytes = elems lane*4..+3 in k order
    yr[lane + 64] = (uint32_t)w1;
}

// -------- fused S = cn·enT GEMM (MX-scaled fp8, 16x16x128, scale=1.0) + exp + reductions ----
// Round-11 (third re-run; rounds 5, 6, 7 were infra failures, no data):
// round-10 fixed the spill (FETCH/WRITE back to 18.5/20.5 MB, VGPR 172,
// absmax 0) but exposed a latency bottleneck: occupancy ~1 block/CU (10.8%) and a
// fully-serial per-stage structure (barrier -> issue loads -> vmcnt(0) drain ->
// compute) meant every stage ate the raw ~200-900 cyc load latency; MfmaUtil 9.9%,
// VALUBusy 14%, ALL pipes idle -> 134 us. Round 7 survived the same serial loop only
// via ~3 blocks/CU of cross-block overlap, which the MX register pressure killed.
// Fix: DOUBLE-BUFFERED LDS (T3-minimal 2-phase): issue stage t+1's global_load_lds
// into buf^1 BEFORE computing buf (write-safety: barrier at end of iter t-1 was the
// last reader's fence), so the vmcnt(0) drain in the trailing __syncthreads lands
// after ~1k cycles of ds_read+MFMA. LDS 32->64 KB/block (still 2 blocks/CU max).
// Bank-conflict note: the exact-2^22 SQ_LDS_BANK_CONFLICT persists across codegen
// variants -> real, tied to the MX fragment-read pattern, but only ~5% of cycles.
// MX math unchanged (verified absmax 0 three rounds running): scales pinned 0x7F.
__global__ __launch_bounds__(256, 1) void gemm_loss_kernel(
    const uint8_t* __restrict__ A,   // cn fp8 [N][512 B]
    const uint8_t* __restrict__ B,   // en fp8 [N][512 B]
    const float* __restrict__ temp_p,
    float* __restrict__ rowsum,
    float* __restrict__ colsum,
    float* __restrict__ diagv)
{
    __shared__ uint8_t As[2][TILE * BKB];   // 2 x 16 KB
    __shared__ uint8_t Bs[2][TILE * BKB];   // 2 x 16 KB

    const int tid  = threadIdx.x;
    const int lane = tid & 63;
    const int wv   = tid >> 6;          // wave 0..3
    const int wi   = (wv >> 1) * 64;    // wave row offset in tile
    const int wj   = (wv & 1) * 64;     // wave col offset in tile
    const int lcol = lane & 15;
    const int q    = lane >> 4;
    const int u0   = q << 1;            // first 16B k-unit this lane feeds to MFMA

    const int bi = blockIdx.x & (NBLK - 1);
    const int bj = blockIdx.x >> 6;
    const int row0 = bi * TILE;
    const int col0 = bj * TILE;

    // staging: wave wv loads rows [wv*32, wv*32+32) of both tiles, 4 chunks of 8 rows
    const int sr = lane >> 3;            // row within 8-row chunk
    const int su = (lane & 7) ^ sr;      // 16B-unit fetched by this lane (swizzle inverse)
    const uint8_t* Ag = A + (size_t)(row0 + wv * 32 + sr) * DDIM + su * 16;
    const uint8_t* Bg = B + (size_t)(col0 + wv * 32 + sr) * DDIM + su * 16;

    f32x4 acc[4][4] = {};
    const int SC1 = 0x7F7F7F7F;          // E8M0 scale 1.0 in every byte

    // issue one stage's 8 async bursts (this wave's 32-row slice of A and B)
    auto stage = [&](int buf, int k0) {
        #pragma unroll
        for (int c = 0; c < 4; ++c) {
            async_copy16(Ag + (size_t)(c * 8) * DDIM + k0, &As[buf][(wv * 32 + c * 8) * BKB]);
            async_copy16(Bg + (size_t)(c * 8) * DDIM + k0, &Bs[buf][(wv * 32 + c * 8) * BKB]);
        }
    };

    stage(0, 0);
    __syncthreads();   // drain stage-0 loads (vmcnt 0) + barrier

    #pragma unroll
    for (int t = 0; t < 4; ++t) {      // t, cur, buf indices all compile-time
        const int cur = t & 1;
        if (t < 3) stage(cur ^ 1, (t + 1) * BKB);   // prefetch next stage, no wait

        #pragma unroll
        for (int nt2 = 0; nt2 < 2; ++nt2) {
            // hold 2 B fragments (16 regs)
            i32x8 bf2[2];
            #pragma unroll
            for (int j = 0; j < 2; ++j) {
                const int r = wj + (nt2 * 2 + j) * 16 + lcol;
                const uint8_t* base = &Bs[cur][r * BKB];
                i32x4 lo = *(const i32x4*)&base[((u0    ) ^ (r & 7)) * 16];
                i32x4 hi = *(const i32x4*)&base[((u0 + 1) ^ (r & 7)) * 16];
                bf2[j] = __builtin_shufflevector(lo, hi, 0, 1, 2, 3, 4, 5, 6, 7);
            }
            // stream A fragments: each built just before its 2 MFMAs, then dead
            #pragma unroll
            for (int mt = 0; mt < 4; ++mt) {
                const int r = wi + mt * 16 + lcol;
                const uint8_t* base = &As[cur][r * BKB];
                i32x4 lo = *(const i32x4*)&base[((u0    ) ^ (r & 7)) * 16];
                i32x4 hi = *(const i32x4*)&base[((u0 + 1) ^ (r & 7)) * 16];
                i32x8 af = __builtin_shufflevector(lo, hi, 0, 1, 2, 3, 4, 5, 6, 7);
                acc[mt][nt2 * 2]     = __builtin_amdgcn_mfma_scale_f32_16x16x128_f8f6f4(
                    af, bf2[0], acc[mt][nt2 * 2],
                    0 /*cbsz: A=fp8 e4m3*/, 0 /*blgp: B=fp8 e4m3*/,
                    0, SC1, 0, SC1);
                acc[mt][nt2 * 2 + 1] = __builtin_amdgcn_mfma_scale_f32_16x16x128_f8f6f4(
                    af, bf2[1], acc[mt][nt2 * 2 + 1],
                    0, 0, 0, SC1, 0, SC1);
            }
        }

        if (t < 3) __syncthreads();   // drains prefetch vmcnt(0) AFTER compute + barrier
    }

    // ---- epilogue: e = exp(s - M) = 2^(c2*acc - c2), M = 1/T (max possible) ----
    const float invT = 1.0f / temp_p[0];
    const float c2   = invT * 1.442695040888963f;   // log2(e)/T

    float rs[4][4];   // per-lane row partials [mt][reg]
    float cs[4];      // per-lane col partials [nt]
    #pragma unroll
    for (int mt = 0; mt < 4; ++mt)
        #pragma unroll
        for (int r = 0; r < 4; ++r) rs[mt][r] = 0.f;
    #pragma unroll
    for (int nt = 0; nt < 4; ++nt) cs[nt] = 0.f;

    #pragma unroll
    for (int mt = 0; mt < 4; ++mt) {
        #pragma unroll
        for (int nt = 0; nt < 4; ++nt) {
            #pragma unroll
            for (int r = 0; r < 4; ++r) {
                // C/D layout: col = lane&15, row = quad*4 + reg  [m89/m91]
                const int gi = row0 + wi + mt * 16 + q * 4 + r;
                const int gj = col0 + wj + nt * 16 + lcol;
                const float a = acc[mt][nt][r];
                float e;
                if (gi == gj) { diagv[gi] = a * invT; e = 0.f; }
                else          { e = __builtin_amdgcn_exp2f(fmaf(a, c2, -c2)); }
                rs[mt][r] += e;
                cs[nt]    += e;
            }
        }
    }

    // row sums: reduce across the 16 columns (lane bits 0..3)
    #pragma unroll
    for (int d = 1; d < 16; d <<= 1)
        #pragma unroll
        for (int mt = 0; mt < 4; ++mt)
            #pragma unroll
            for (int r = 0; r < 4; ++r)
                rs[mt][r] += __shfl_xor(rs[mt][r], d);

    // col sums: reduce across the 4 quads (lane bits 4..5)
    #pragma unroll
    for (int d = 16; d < 64; d <<= 1)
        #pragma unroll
        for (int nt = 0; nt < 4; ++nt)
            cs[nt] += __shfl_xor(cs[nt], d);

    if (lcol == 0) {
        #pragma unroll
        for (int mt = 0; mt < 4; ++mt)
            #pragma unroll
            for (int r = 0; r < 4; ++r)
                atomicAdd(&rowsum[row0 + wi + mt * 16 + q * 4 + r], rs[mt][r]);
    }
    if (q == 0) {
        #pragma unroll
        for (int nt = 0; nt < 4; ++nt)
            atomicAdd(&colsum[col0 + wj + nt * 16 + lcol], cs[nt]);
    }
}

// -------- final scalar: loss = mean_i( 2M + log(rowsum_i) + log(colsum_i) - 2*diag_i ) ----
__global__ __launch_bounds__(256) void finalize_kernel(
    const float* __restrict__ rowsum, const float* __restrict__ colsum,
    const float* __restrict__ diagv,  const float* __restrict__ temp_p,
    float* __restrict__ out)
{
    __shared__ float red[4];
    const float M = 1.0f / temp_p[0];
    const int i = blockIdx.x * 256 + threadIdx.x;
    float s = 2.f * M + logf(rowsum[i]) + logf(colsum[i]) - 2.f * diagv[i];
    #pragma unroll
    for (int d = 1; d < 64; d <<= 1) s += __shfl_xor(s, d);
    if ((threadIdx.x & 63) == 0) red[threadIdx.x >> 6] = s;
    __syncthreads();
    if (threadIdx.x == 0)
        atomicAdd(out, (red[0] + red[1] + red[2] + red[3]) / (float)NROWS);
}

extern "C" void kernel_launch(void* const* d_in, const int* in_sizes, int n_in,
                              void* d_out, int out_size, void* d_ws, size_t ws_size,
                              hipStream_t stream) {
    (void)in_sizes; (void)n_in; (void)out_size; (void)ws_size;
    const float* cxr    = (const float*)d_in[0];
    const float* ehr    = (const float*)d_in[1];
    const float* temp_p = (const float*)d_in[2];
    float* out = (float*)d_out;

    // workspace: rowsum[N] | colsum[N] | diag[N] | cn fp8 [N*512B] | en fp8 (~8.1 MB)
    float* rowsum = (float*)d_ws;
    float* colsum = rowsum + NROWS;
    float* diagv  = colsum + NROWS;
    uint32_t* cn8 = (uint32_t*)(diagv + NROWS);            // 16B-aligned (96 KB offset)
    uint32_t* en8 = cn8 + (size_t)NROWS * (DDIM / 4);
    const uint8_t* cnb = (const uint8_t*)cn8;
    const uint8_t* enb = (const uint8_t*)en8;

    prep_kernel<<<4096, 256, 0, stream>>>(cxr, ehr, cn8, en8, rowsum, out);
    gemm_loss_kernel<<<NBLK * NBLK, 256, 0, stream>>>(cnb, enb, temp_p, rowsum, colsum, diagv);
    finalize_kernel<<<NROWS / 256, 256, 0, stream>>>(rowsum, colsum, diagv, temp_p, out);
}